// Round 6
// baseline (932.303 us; speedup 1.0000x reference)
//
#include <hip/hip_runtime.h>
#include <hip/hip_bf16.h>

#define B_   8
#define TQ_  8
#define TP_  447
#define TC_  1500
#define D_   1280
#define H_   20
#define DH_  64
#define DFF_ 5120
#define M_   64    // B_*TQ_ total rows

// ================= LayerNorm: row-major fp32 input -> transposed f32 [D_][M_]
__global__ __launch_bounds__(256) void ln_kernel(const float* __restrict__ X,
    const float* __restrict__ g, const float* __restrict__ be, float* __restrict__ outT)
{
  __shared__ float redA[4], redB[4];
  const int m = blockIdx.x;
  const int tid = threadIdx.x;
  float v[5];
#pragma unroll
  for (int t = 0; t < 5; ++t) v[t] = X[(size_t)m*D_ + tid + t*256];
  float s = v[0]+v[1]+v[2]+v[3]+v[4];
#pragma unroll
  for (int o = 32; o; o >>= 1) s += __shfl_down(s, o, 64);
  if ((tid & 63) == 0) redA[tid >> 6] = s;
  __syncthreads();
  const float mean = (redA[0]+redA[1]+redA[2]+redA[3]) * (1.0f/D_);
  float q = 0.f;
#pragma unroll
  for (int t = 0; t < 5; ++t) { const float d = v[t]-mean; q += d*d; }
#pragma unroll
  for (int o = 32; o; o >>= 1) q += __shfl_down(q, o, 64);
  if ((tid & 63) == 0) redB[tid >> 6] = q;
  __syncthreads();
  const float rstd = rsqrtf((redB[0]+redB[1]+redB[2]+redB[3]) * (1.0f/D_) + 1e-5f);
#pragma unroll
  for (int t = 0; t < 5; ++t) {
    const int c = tid + t*256;
    outT[(size_t)c*M_ + m] = (v[t]-mean)*rstd*g[c] + be[c];
  }
}

// ================= split-K GEMM: P[s][m][n] = sum_{k in chunk s} XT[k][m]*W[k][n]
__global__ __launch_bounds__(256) void gemm_splitk(
    const float* __restrict__ XT,
    const float* __restrict__ Wa, const float* __restrict__ Wb, const float* __restrict__ Wc,
    float* __restrict__ Pa, float* __restrict__ Pb, float* __restrict__ Pc,
    int N, int chunk)
{
  __shared__ float xs[64][64];
  const int z = blockIdx.z;
  const float* W = (z == 0 ? Wa : (z == 1 ? Wb : Wc));
  float* P = (z == 0 ? Pa : (z == 1 ? Pb : Pc));
  const int tid  = threadIdx.x;
  const int lane = tid & 63;
  const int wv   = tid >> 6;
  const int n    = blockIdx.x*128 + lane*2;
  const int k0   = blockIdx.y * chunk;
  float accL[16], accH[16];
#pragma unroll
  for (int r = 0; r < 16; ++r) { accL[r] = 0.f; accH[r] = 0.f; }

  for (int kb = 0; kb < chunk; kb += 64) {
    __syncthreads();
    {
      const float4* src = (const float4*)(XT + (size_t)(k0 + kb)*M_);
      float4* dst = (float4*)&xs[0][0];
#pragma unroll
      for (int i = 0; i < 4; ++i) dst[tid + i*256] = src[tid + i*256];
    }
    __syncthreads();
    const float* Wp = W + (size_t)(k0 + kb)*N + n;
    for (int kk = 0; kk < 64; ++kk) {
      const float2 wp = *(const float2*)(Wp + (size_t)kk*N);
      const float wl = wp.x;
      const float wh = wp.y;
      const float* xr = &xs[kk][wv*16];
#pragma unroll
      for (int r4 = 0; r4 < 4; ++r4) {
        const float4 xv = *(const float4*)(xr + r4*4);
        accL[r4*4+0] += xv.x*wl; accH[r4*4+0] += xv.x*wh;
        accL[r4*4+1] += xv.y*wl; accH[r4*4+1] += xv.y*wh;
        accL[r4*4+2] += xv.z*wl; accH[r4*4+2] += xv.z*wh;
        accL[r4*4+3] += xv.w*wl; accH[r4*4+3] += xv.w*wh;
      }
    }
  }
#pragma unroll
  for (int r = 0; r < 16; ++r) {
    const int m = wv*16 + r;
    float2 st; st.x = accL[r]; st.y = accH[r];
    *(float2*)(P + ((size_t)blockIdx.y*M_ + m)*N + n) = st;
  }
}

// ================= epilogue: sum split-K partials, +bias, gelu, +residual, multi-format out
__global__ __launch_bounds__(256) void epilogue_kernel(
    const float* __restrict__ P, int S, int N,
    const float* __restrict__ bias,
    const float* __restrict__ res,
    int gelu,
    float* __restrict__ outA, float* __restrict__ outT, float* __restrict__ outB)
{
  const int idx = blockIdx.x*256 + threadIdx.x;   // < M_*N
  const int m = idx / N;
  const int n = idx - m*N;
  float a = 0.f;
  for (int s = 0; s < S; ++s) a += P[((size_t)s*M_ + m)*N + n];
  if (bias) a += bias[n];
  if (gelu) a = 0.5f*a*(1.0f + erff(a*0.70710678118654752f));
  if (res) a += res[idx];
  if (outA) outA[idx] = a;
  if (outT) outT[(size_t)n*M_ + m] = a;
  if (outB) outB[idx] = a;
}

// ================= fused attention split: scores + softmax (LDS) + PV partial
// grid (SP, H_, B_), block 256. chunk <= 128.
// Q: [M_][D_] f32 RM. Kc/Vc: [B][TPp][D_] f32. Kn/Vn: [M_][D_] f32 (new rows) or null.
// Opart: per (bh,sp): [8][64]. ML: per (bh,sp): [16] = {max[8] | sum[8]}.
// SCS=10: gcd(10,32)=2 -> 2-way LDS aliasing (free, m136); jl*10+even keeps 8B align.
#define SCS 10
__global__ __launch_bounds__(256, 4) void attn_fused(
    const float* __restrict__ Q,
    const float* __restrict__ Kc, const float* __restrict__ Kn,
    const float* __restrict__ Vc, const float* __restrict__ Vn,
    const float* __restrict__ mask,
    float* __restrict__ Opart, float* __restrict__ ML,
    int TK, int TPp, int chunk)
{
  __shared__ float sc[128*SCS];     // scores then exp-weights, [jl][SCS]
  __shared__ float qs[8*64];        // q rows for this (b,*,h)
  const int tid = threadIdx.x;
  const int sp = blockIdx.x, h = blockIdx.y, b = blockIdx.z;
  const int SP = gridDim.x;
  const int j0 = sp * chunk;
  const int cnt = min(chunk, TK - j0);
  const int bh = b*H_ + h;

  // stage q: 512 floats
  {
    const int i = tid >> 6, d = tid & 63;
    qs[tid]       = Q[((size_t)(b*TQ_ + i    ))*D_ + h*DH_ + d];
    qs[tid + 256] = Q[((size_t)(b*TQ_ + i + 4))*D_ + h*DH_ + d];
  }
  __syncthreads();

  // ---- phase 1: scores (thread per key row) ----
  for (int jl = tid; jl < cnt; jl += 256) {
    const int j = j0 + jl;
    const float* kr = (j < TPp)
      ? Kc + ((size_t)b*TPp + j)*D_ + h*DH_
      : Kn + ((size_t)(b*TQ_ + (j - TPp)))*D_ + h*DH_;
    float acc[8] = {0.f,0.f,0.f,0.f,0.f,0.f,0.f,0.f};
#pragma unroll
    for (int dc = 0; dc < 16; ++dc) {
      const float4 kf = *(const float4*)(kr + dc*4);
#pragma unroll
      for (int i = 0; i < 8; ++i) {
        const float4 qv = *(const float4*)&qs[i*64 + dc*4];
        acc[i] += qv.x*kf.x + qv.y*kf.y + qv.z*kf.z + qv.w*kf.w;
      }
    }
#pragma unroll
    for (int i = 0; i < 8; ++i) {
      float vv = acc[i]*0.125f;       // (dh^-0.25)^2 on the q.k product
      if (mask) vv += mask[(size_t)i*TK + j];
      sc[jl*SCS + i] = vv;
    }
  }
  __syncthreads();

  // ---- phase 2: per-split softmax, exp in place; 8 row-groups x 32 lanes ----
  {
    const int g = tid >> 5, l = tid & 31;
    float mx = -3.0e38f;
    for (int jl = l; jl < cnt; jl += 32) mx = fmaxf(mx, sc[jl*SCS + g]);
#pragma unroll
    for (int o = 16; o; o >>= 1) mx = fmaxf(mx, __shfl_down(mx, o, 32));
    mx = __shfl(mx, 0, 32);
    float sum = 0.f;
    for (int jl = l; jl < cnt; jl += 32) {
      const float e = __expf(sc[jl*SCS + g] - mx);
      sc[jl*SCS + g] = e;
      sum += e;
    }
#pragma unroll
    for (int o = 16; o; o >>= 1) sum += __shfl_down(sum, o, 32);
    if (l == 0) {
      ML[((size_t)bh*SP + sp)*16 + g]     = mx;
      ML[((size_t)bh*SP + sp)*16 + 8 + g] = sum;
    }
  }
  __syncthreads();

  // ---- phase 3: PV. Wave wv owns q-rows 2wv,2wv+1; lane = d; P via LDS broadcast ----
  {
    const int wv = tid >> 6;
    const int d  = tid & 63;
    const int i0 = wv*2;
    float a0 = 0.f, a1 = 0.f;
    for (int jl = 0; jl < cnt; ++jl) {
      const int j = j0 + jl;
      const float vv = (j < TPp)
        ? Vc[((size_t)b*TPp + j)*D_ + h*DH_ + d]
        : Vn[((size_t)(b*TQ_ + (j - TPp)))*D_ + h*DH_ + d];
      const float2 p = *(const float2*)&sc[jl*SCS + i0];   // broadcast, conflict-free
      a0 += p.x*vv;
      a1 += p.y*vv;
    }
    Opart[(((size_t)bh*SP + sp)*8 + i0    )*64 + d] = a0;
    Opart[(((size_t)bh*SP + sp)*8 + i0 + 1)*64 + d] = a1;
  }
}

// ================= merge PV partials with split-softmax weights; outT f32 [D_][M_]
__global__ __launch_bounds__(256) void attn_pv_combine(
    const float* __restrict__ Opart, const float* __restrict__ ML,
    float* __restrict__ outT, int SP)
{
  const int tid = threadIdx.x;
  const int h = blockIdx.x, b = blockIdx.y;
  const int bh = b*H_ + h;
  const int wv = tid >> 6, d = tid & 63;
  const int i0 = wv*2, i1 = i0 + 1;
  float M0 = -3.0e38f, M1 = -3.0e38f;
  for (int s = 0; s < SP; ++s) {
    M0 = fmaxf(M0, ML[((size_t)bh*SP + s)*16 + i0]);
    M1 = fmaxf(M1, ML[((size_t)bh*SP + s)*16 + i1]);
  }
  float L0 = 0.f, L1 = 0.f, o0 = 0.f, o1 = 0.f;
  for (int s = 0; s < SP; ++s) {
    const float w0 = __expf(ML[((size_t)bh*SP + s)*16 + i0] - M0);
    const float w1 = __expf(ML[((size_t)bh*SP + s)*16 + i1] - M1);
    L0 += w0 * ML[((size_t)bh*SP + s)*16 + 8 + i0];
    L1 += w1 * ML[((size_t)bh*SP + s)*16 + 8 + i1];
    o0 += w0 * Opart[(((size_t)bh*SP + s)*8 + i0)*64 + d];
    o1 += w1 * Opart[(((size_t)bh*SP + s)*8 + i1)*64 + d];
  }
  outT[((size_t)(h*DH_ + d))*M_ + b*TQ_ + i0] = o0 / L0;
  outT[((size_t)(h*DH_ + d))*M_ + b*TQ_ + i1] = o1 / L1;
}

extern "C" void kernel_launch(void* const* d_in, const int* in_sizes, int n_in,
                              void* d_out, int out_size, void* d_ws, size_t ws_size,
                              hipStream_t stream)
{
  (void)in_sizes; (void)n_in; (void)out_size; (void)ws_size;
  const float* x    = (const float*)d_in[0];
  const float* skc  = (const float*)d_in[1];
  const float* svc  = (const float*)d_in[2];
  const float* ck   = (const float*)d_in[3];
  const float* cv   = (const float*)d_in[4];
  const float* msk  = (const float*)d_in[5];
  const float* wq   = (const float*)d_in[6];
  const float* bq   = (const float*)d_in[7];
  const float* wk   = (const float*)d_in[8];
  const float* wvv  = (const float*)d_in[9];
  const float* bv   = (const float*)d_in[10];
  const float* wo   = (const float*)d_in[11];
  const float* bo   = (const float*)d_in[12];
  const float* cwq  = (const float*)d_in[13];
  const float* cbq  = (const float*)d_in[14];
  const float* cwo  = (const float*)d_in[15];
  const float* cbo  = (const float*)d_in[16];
  const float* ln1w = (const float*)d_in[17];
  const float* ln1b = (const float*)d_in[18];
  const float* ln2w = (const float*)d_in[19];
  const float* ln2b = (const float*)d_in[20];
  const float* ln3w = (const float*)d_in[21];
  const float* ln3b = (const float*)d_in[22];
  const float* w1   = (const float*)d_in[23];
  const float* b1   = (const float*)d_in[24];
  const float* w2   = (const float*)d_in[25];
  const float* b2   = (const float*)d_in[26];
  // d_in[27] = offset (int) — fixed at TP_ here.

  float* out_x  = (float*)d_out;
  float* out_k1 = out_x + 81920;
  float* out_v1 = out_x + 163840;

  float* ws = (float*)d_ws;
  float* xlT  = ws + 0;               // [1280][64], reused 3x
  float* qbuf = ws + 81920;           // q / qc row-major [64][1280]
  float* k1f  = ws + 163840;
  float* v1f  = ws + 245760;
  float* x2   = ws + 327680;
  float* x3   = ws + 409600;
  float* attT = ws + 491520;          // attn out transposed, reused 2x
  float* hT   = ws + 573440;          // [5120][64]
  float* Pg   = ws + 901120;          // split-K partials / attention Opart
  float* Pq   = Pg;
  float* Pk   = Pg + 819200;
  float* Pv   = Pg + 1638400;
  float* MLS  = ws + 4177920;         // 160*8*16
  float* MLC  = ws + 4218880;         // 160*16*16

  const dim3 blk(256);

  // --- self-attention ---
  ln_kernel<<<dim3(64), blk, 0, stream>>>(x, ln1w, ln1b, xlT);
  gemm_splitk<<<dim3(10,10,3), blk, 0, stream>>>(xlT, wq, wk, wvv, Pq, Pk, Pv, 1280, 128);
  epilogue_kernel<<<dim3(320), blk, 0, stream>>>(Pq, 10, 1280, bq, nullptr, 0, qbuf, nullptr, nullptr);
  epilogue_kernel<<<dim3(320), blk, 0, stream>>>(Pk, 10, 1280, nullptr, nullptr, 0, k1f, nullptr, out_k1);
  epilogue_kernel<<<dim3(320), blk, 0, stream>>>(Pv, 10, 1280, bv, nullptr, 0, v1f, nullptr, out_v1);
  // SP=8, chunk=57 (8*57=456 >= 455)
  attn_fused<<<dim3(8,20,8), blk, 0, stream>>>(qbuf, skc, k1f, svc, v1f, msk, Pg, MLS, 455, 447, 57);
  attn_pv_combine<<<dim3(20,8), blk, 0, stream>>>(Pg, MLS, attT, 8);
  gemm_splitk<<<dim3(10,10,1), blk, 0, stream>>>(attT, wo, wo, wo, Pq, Pq, Pq, 1280, 128);
  epilogue_kernel<<<dim3(320), blk, 0, stream>>>(Pq, 10, 1280, bo, x, 0, x2, nullptr, nullptr);

  // --- cross-attention ---
  ln_kernel<<<dim3(64), blk, 0, stream>>>(x2, ln2w, ln2b, xlT);
  gemm_splitk<<<dim3(10,10,1), blk, 0, stream>>>(xlT, cwq, cwq, cwq, Pq, Pq, Pq, 1280, 128);
  epilogue_kernel<<<dim3(320), blk, 0, stream>>>(Pq, 10, 1280, cbq, nullptr, 0, qbuf, nullptr, nullptr);
  // SP=16, chunk=94 (16*94=1504 >= 1500)
  attn_fused<<<dim3(16,20,8), blk, 0, stream>>>(qbuf, ck, nullptr, cv, nullptr, nullptr, Pg, MLC, 1500, 1500, 94);
  attn_pv_combine<<<dim3(20,8), blk, 0, stream>>>(Pg, MLC, attT, 16);
  gemm_splitk<<<dim3(10,10,1), blk, 0, stream>>>(attT, cwo, cwo, cwo, Pq, Pq, Pq, 1280, 128);
  epilogue_kernel<<<dim3(320), blk, 0, stream>>>(Pq, 10, 1280, cbo, x2, 0, x3, nullptr, nullptr);

  // --- MLP ---
  ln_kernel<<<dim3(64), blk, 0, stream>>>(x3, ln3w, ln3b, xlT);
  gemm_splitk<<<dim3(40,10,1), blk, 0, stream>>>(xlT, w1, w1, w1, Pg, Pg, Pg, 5120, 128);
  epilogue_kernel<<<dim3(1280), blk, 0, stream>>>(Pg, 10, 5120, b1, nullptr, 1, nullptr, hT, nullptr);
  gemm_splitk<<<dim3(10,40,1), blk, 0, stream>>>(hT, w2, w2, w2, Pg, Pg, Pg, 1280, 128);
  epilogue_kernel<<<dim3(320), blk, 0, stream>>>(Pg, 40, 1280, b2, x3, 0, nullptr, nullptr, out_x);
}

// Round 7
// 592.799 us; speedup vs baseline: 1.5727x; 1.5727x over previous
//
#include <hip/hip_runtime.h>
#include <hip/hip_bf16.h>

#define B_   8
#define TQ_  8
#define TP_  447
#define TC_  1500
#define D_   1280
#define H_   20
#define DH_  64
#define DFF_ 5120
#define M_   64    // B_*TQ_ total rows

// ================= LayerNorm: row-major fp32 input -> transposed f32 [D_][M_]
__global__ __launch_bounds__(256) void ln_kernel(const float* __restrict__ X,
    const float* __restrict__ g, const float* __restrict__ be, float* __restrict__ outT)
{
  __shared__ float redA[4], redB[4];
  const int m = blockIdx.x;
  const int tid = threadIdx.x;
  float v[5];
#pragma unroll
  for (int t = 0; t < 5; ++t) v[t] = X[(size_t)m*D_ + tid + t*256];
  float s = v[0]+v[1]+v[2]+v[3]+v[4];
#pragma unroll
  for (int o = 32; o; o >>= 1) s += __shfl_down(s, o, 64);
  if ((tid & 63) == 0) redA[tid >> 6] = s;
  __syncthreads();
  const float mean = (redA[0]+redA[1]+redA[2]+redA[3]) * (1.0f/D_);
  float q = 0.f;
#pragma unroll
  for (int t = 0; t < 5; ++t) { const float d = v[t]-mean; q += d*d; }
#pragma unroll
  for (int o = 32; o; o >>= 1) q += __shfl_down(q, o, 64);
  if ((tid & 63) == 0) redB[tid >> 6] = q;
  __syncthreads();
  const float rstd = rsqrtf((redB[0]+redB[1]+redB[2]+redB[3]) * (1.0f/D_) + 1e-5f);
#pragma unroll
  for (int t = 0; t < 5; ++t) {
    const int c = tid + t*256;
    outT[(size_t)c*M_ + m] = (v[t]-mean)*rstd*g[c] + be[c];
  }
}

// ================= split-K GEMM: P[s][m][n] = sum_{k in chunk s} XT[k][m]*W[k][n]
__global__ __launch_bounds__(256) void gemm_splitk(
    const float* __restrict__ XT,
    const float* __restrict__ Wa, const float* __restrict__ Wb, const float* __restrict__ Wc,
    float* __restrict__ Pa, float* __restrict__ Pb, float* __restrict__ Pc,
    int N, int chunk)
{
  __shared__ float xs[64][64];
  const int z = blockIdx.z;
  const float* W = (z == 0 ? Wa : (z == 1 ? Wb : Wc));
  float* P = (z == 0 ? Pa : (z == 1 ? Pb : Pc));
  const int tid  = threadIdx.x;
  const int lane = tid & 63;
  const int wv   = tid >> 6;
  const int n    = blockIdx.x*128 + lane*2;
  const int k0   = blockIdx.y * chunk;
  float accL[16], accH[16];
#pragma unroll
  for (int r = 0; r < 16; ++r) { accL[r] = 0.f; accH[r] = 0.f; }

  for (int kb = 0; kb < chunk; kb += 64) {
    __syncthreads();
    {
      const float4* src = (const float4*)(XT + (size_t)(k0 + kb)*M_);
      float4* dst = (float4*)&xs[0][0];
#pragma unroll
      for (int i = 0; i < 4; ++i) dst[tid + i*256] = src[tid + i*256];
    }
    __syncthreads();
    const float* Wp = W + (size_t)(k0 + kb)*N + n;
    for (int kk = 0; kk < 64; ++kk) {
      const float2 wp = *(const float2*)(Wp + (size_t)kk*N);
      const float wl = wp.x;
      const float wh = wp.y;
      const float* xr = &xs[kk][wv*16];
#pragma unroll
      for (int r4 = 0; r4 < 4; ++r4) {
        const float4 xv = *(const float4*)(xr + r4*4);
        accL[r4*4+0] += xv.x*wl; accH[r4*4+0] += xv.x*wh;
        accL[r4*4+1] += xv.y*wl; accH[r4*4+1] += xv.y*wh;
        accL[r4*4+2] += xv.z*wl; accH[r4*4+2] += xv.z*wh;
        accL[r4*4+3] += xv.w*wl; accH[r4*4+3] += xv.w*wh;
      }
    }
  }
#pragma unroll
  for (int r = 0; r < 16; ++r) {
    const int m = wv*16 + r;
    float2 st; st.x = accL[r]; st.y = accH[r];
    *(float2*)(P + ((size_t)blockIdx.y*M_ + m)*N + n) = st;
  }
}

// ================= epilogue: sum split-K partials, +bias, gelu, +residual, multi-format out
__global__ __launch_bounds__(256) void epilogue_kernel(
    const float* __restrict__ P, int S, int N,
    const float* __restrict__ bias,
    const float* __restrict__ res,
    int gelu,
    float* __restrict__ outA, float* __restrict__ outT, float* __restrict__ outB)
{
  const int idx = blockIdx.x*256 + threadIdx.x;   // < M_*N
  const int m = idx / N;
  const int n = idx - m*N;
  float a = 0.f;
  for (int s = 0; s < S; ++s) a += P[((size_t)s*M_ + m)*N + n];
  if (bias) a += bias[n];
  if (gelu) a = 0.5f*a*(1.0f + erff(a*0.70710678118654752f));
  if (res) a += res[idx];
  if (outA) outA[idx] = a;
  if (outT) outT[(size_t)n*M_ + m] = a;
  if (outB) outB[idx] = a;
}

// ================= fused attention split: scores + softmax (LDS) + PV partial
// grid (SP, H_, B_), block 256. chunk <= 128.
// Q: [M_][D_] f32 RM. Kc/Vc: [B][TPp][D_] f32. Kn/Vn: [M_][D_] f32 (new rows) or null.
// Opart: per (bh,sp): [8][64]. ML: per (bh,sp): [16] = {max[8] | sum[8]}.
// SCS=10: gcd(10,32)=2 -> 2-way LDS aliasing (free, m136); jl*10+even keeps 8B align.
#define SCS 10
__global__ __launch_bounds__(256, 4) void attn_fused(
    const float* __restrict__ Q,
    const float* __restrict__ Kc, const float* __restrict__ Kn,
    const float* __restrict__ Vc, const float* __restrict__ Vn,
    const float* __restrict__ mask,
    float* __restrict__ Opart, float* __restrict__ ML,
    int TK, int TPp, int chunk)
{
  __shared__ float sc[128*SCS];     // scores then exp-weights, [jl][SCS]
  __shared__ float qs[8*64];        // q rows for this (b,*,h)
  __shared__ float red[4*8*64];     // per-wave PV partials (8 KB)
  const int tid = threadIdx.x;
  const int sp = blockIdx.x, h = blockIdx.y, b = blockIdx.z;
  const int SP = gridDim.x;
  const int j0 = sp * chunk;
  const int cnt = min(chunk, TK - j0);
  const int bh = b*H_ + h;

  // stage q: 512 floats
  {
    const int i = tid >> 6, d = tid & 63;
    qs[tid]       = Q[((size_t)(b*TQ_ + i    ))*D_ + h*DH_ + d];
    qs[tid + 256] = Q[((size_t)(b*TQ_ + i + 4))*D_ + h*DH_ + d];
  }
  __syncthreads();

  // ---- phase 1: scores (thread per key row) ----
  for (int jl = tid; jl < cnt; jl += 256) {
    const int j = j0 + jl;
    const float* kr = (j < TPp)
      ? Kc + ((size_t)b*TPp + j)*D_ + h*DH_
      : Kn + ((size_t)(b*TQ_ + (j - TPp)))*D_ + h*DH_;
    float acc[8] = {0.f,0.f,0.f,0.f,0.f,0.f,0.f,0.f};
#pragma unroll 8
    for (int dc = 0; dc < 16; ++dc) {
      const float4 kf = *(const float4*)(kr + dc*4);
#pragma unroll
      for (int i = 0; i < 8; ++i) {
        const float4 qv = *(const float4*)&qs[i*64 + dc*4];
        acc[i] += qv.x*kf.x + qv.y*kf.y + qv.z*kf.z + qv.w*kf.w;
      }
    }
#pragma unroll
    for (int i = 0; i < 8; ++i) {
      float vv = acc[i]*0.125f;       // (dh^-0.25)^2 on the q.k product
      if (mask) vv += mask[(size_t)i*TK + j];
      sc[jl*SCS + i] = vv;
    }
  }
  __syncthreads();

  // ---- phase 2: per-split softmax, exp in place; 8 row-groups x 32 lanes ----
  {
    const int g = tid >> 5, l = tid & 31;
    float mx = -3.0e38f;
    for (int jl = l; jl < cnt; jl += 32) mx = fmaxf(mx, sc[jl*SCS + g]);
#pragma unroll
    for (int o = 16; o; o >>= 1) mx = fmaxf(mx, __shfl_down(mx, o, 32));
    mx = __shfl(mx, 0, 32);
    float sum = 0.f;
    for (int jl = l; jl < cnt; jl += 32) {
      const float e = __expf(sc[jl*SCS + g] - mx);
      sc[jl*SCS + g] = e;
      sum += e;
    }
#pragma unroll
    for (int o = 16; o; o >>= 1) sum += __shfl_down(sum, o, 32);
    if (l == 0) {
      ML[((size_t)bh*SP + sp)*16 + g]     = mx;
      ML[((size_t)bh*SP + sp)*16 + 8 + g] = sum;
    }
  }
  __syncthreads();

  // ---- phase 3: PV. Waves interleave over j (V read ONCE per block, 256B/instr);
  //      lane = d; all 8 q-rows accumulated per lane (8 VGPRs); LDS-broadcast weights ----
  {
    const int wv = tid >> 6;
    const int d  = tid & 63;
    float acc[8] = {0.f,0.f,0.f,0.f,0.f,0.f,0.f,0.f};
#pragma unroll 2
    for (int jl = wv; jl < cnt; jl += 4) {
      const int j = j0 + jl;
      const float vv = (j < TPp)
        ? Vc[((size_t)b*TPp + j)*D_ + h*DH_ + d]
        : Vn[((size_t)(b*TQ_ + (j - TPp)))*D_ + h*DH_ + d];
      const float2 p0 = *(const float2*)&sc[jl*SCS + 0];   // broadcast, conflict-free
      const float2 p1 = *(const float2*)&sc[jl*SCS + 2];
      const float2 p2 = *(const float2*)&sc[jl*SCS + 4];
      const float2 p3 = *(const float2*)&sc[jl*SCS + 6];
      acc[0] += p0.x*vv; acc[1] += p0.y*vv;
      acc[2] += p1.x*vv; acc[3] += p1.y*vv;
      acc[4] += p2.x*vv; acc[5] += p2.y*vv;
      acc[6] += p3.x*vv; acc[7] += p3.y*vv;
    }
#pragma unroll
    for (int i = 0; i < 8; ++i) red[(wv*8 + i)*64 + d] = acc[i];
  }
  __syncthreads();
  {
#pragma unroll
    for (int t = 0; t < 2; ++t) {
      const int o = tid + t*256;        // < 512
      const int i = o >> 6, d = o & 63;
      const float r = red[(0*8 + i)*64 + d] + red[(1*8 + i)*64 + d]
                    + red[(2*8 + i)*64 + d] + red[(3*8 + i)*64 + d];
      Opart[(((size_t)bh*SP + sp)*8 + i)*64 + d] = r;
    }
  }
}

// ================= merge PV partials with split-softmax weights; outT f32 [D_][M_]
__global__ __launch_bounds__(256) void attn_pv_combine(
    const float* __restrict__ Opart, const float* __restrict__ ML,
    float* __restrict__ outT, int SP)
{
  const int tid = threadIdx.x;
  const int h = blockIdx.x, b = blockIdx.y;
  const int bh = b*H_ + h;
  const int wv = tid >> 6, d = tid & 63;
  const int i0 = wv*2, i1 = i0 + 1;
  float M0 = -3.0e38f, M1 = -3.0e38f;
  for (int s = 0; s < SP; ++s) {
    M0 = fmaxf(M0, ML[((size_t)bh*SP + s)*16 + i0]);
    M1 = fmaxf(M1, ML[((size_t)bh*SP + s)*16 + i1]);
  }
  float L0 = 0.f, L1 = 0.f, o0 = 0.f, o1 = 0.f;
  for (int s = 0; s < SP; ++s) {
    const float w0 = __expf(ML[((size_t)bh*SP + s)*16 + i0] - M0);
    const float w1 = __expf(ML[((size_t)bh*SP + s)*16 + i1] - M1);
    L0 += w0 * ML[((size_t)bh*SP + s)*16 + 8 + i0];
    L1 += w1 * ML[((size_t)bh*SP + s)*16 + 8 + i1];
    o0 += w0 * Opart[(((size_t)bh*SP + s)*8 + i0)*64 + d];
    o1 += w1 * Opart[(((size_t)bh*SP + s)*8 + i1)*64 + d];
  }
  outT[((size_t)(h*DH_ + d))*M_ + b*TQ_ + i0] = o0 / L0;
  outT[((size_t)(h*DH_ + d))*M_ + b*TQ_ + i1] = o1 / L1;
}

extern "C" void kernel_launch(void* const* d_in, const int* in_sizes, int n_in,
                              void* d_out, int out_size, void* d_ws, size_t ws_size,
                              hipStream_t stream)
{
  (void)in_sizes; (void)n_in; (void)out_size; (void)ws_size;
  const float* x    = (const float*)d_in[0];
  const float* skc  = (const float*)d_in[1];
  const float* svc  = (const float*)d_in[2];
  const float* ck   = (const float*)d_in[3];
  const float* cv   = (const float*)d_in[4];
  const float* msk  = (const float*)d_in[5];
  const float* wq   = (const float*)d_in[6];
  const float* bq   = (const float*)d_in[7];
  const float* wk   = (const float*)d_in[8];
  const float* wvv  = (const float*)d_in[9];
  const float* bv   = (const float*)d_in[10];
  const float* wo   = (const float*)d_in[11];
  const float* bo   = (const float*)d_in[12];
  const float* cwq  = (const float*)d_in[13];
  const float* cbq  = (const float*)d_in[14];
  const float* cwo  = (const float*)d_in[15];
  const float* cbo  = (const float*)d_in[16];
  const float* ln1w = (const float*)d_in[17];
  const float* ln1b = (const float*)d_in[18];
  const float* ln2w = (const float*)d_in[19];
  const float* ln2b = (const float*)d_in[20];
  const float* ln3w = (const float*)d_in[21];
  const float* ln3b = (const float*)d_in[22];
  const float* w1   = (const float*)d_in[23];
  const float* b1   = (const float*)d_in[24];
  const float* w2   = (const float*)d_in[25];
  const float* b2   = (const float*)d_in[26];
  // d_in[27] = offset (int) — fixed at TP_ here.

  float* out_x  = (float*)d_out;
  float* out_k1 = out_x + 81920;
  float* out_v1 = out_x + 163840;

  float* ws = (float*)d_ws;
  float* xlT  = ws + 0;               // [1280][64], reused 3x
  float* qbuf = ws + 81920;           // q / qc row-major [64][1280]
  float* k1f  = ws + 163840;
  float* v1f  = ws + 245760;
  float* x2   = ws + 327680;
  float* x3   = ws + 409600;
  float* attT = ws + 491520;          // attn out transposed, reused 2x
  float* hT   = ws + 573440;          // [5120][64]
  float* Pg   = ws + 901120;          // split-K partials / attention Opart
  float* Pq   = Pg;
  float* Pk   = Pg + 819200;
  float* Pv   = Pg + 1638400;
  float* MLS  = ws + 4177920;         // 160*8*16
  float* MLC  = ws + 4218880;         // 160*16*16

  const dim3 blk(256);

  // --- self-attention ---
  ln_kernel<<<dim3(64), blk, 0, stream>>>(x, ln1w, ln1b, xlT);
  gemm_splitk<<<dim3(10,10,3), blk, 0, stream>>>(xlT, wq, wk, wvv, Pq, Pk, Pv, 1280, 128);
  epilogue_kernel<<<dim3(320), blk, 0, stream>>>(Pq, 10, 1280, bq, nullptr, 0, qbuf, nullptr, nullptr);
  epilogue_kernel<<<dim3(320), blk, 0, stream>>>(Pk, 10, 1280, nullptr, nullptr, 0, k1f, nullptr, out_k1);
  epilogue_kernel<<<dim3(320), blk, 0, stream>>>(Pv, 10, 1280, bv, nullptr, 0, v1f, nullptr, out_v1);
  // SP=8, chunk=57 (8*57=456 >= 455)
  attn_fused<<<dim3(8,20,8), blk, 0, stream>>>(qbuf, skc, k1f, svc, v1f, msk, Pg, MLS, 455, 447, 57);
  attn_pv_combine<<<dim3(20,8), blk, 0, stream>>>(Pg, MLS, attT, 8);
  gemm_splitk<<<dim3(10,10,1), blk, 0, stream>>>(attT, wo, wo, wo, Pq, Pq, Pq, 1280, 128);
  epilogue_kernel<<<dim3(320), blk, 0, stream>>>(Pq, 10, 1280, bo, x, 0, x2, nullptr, nullptr);

  // --- cross-attention ---
  ln_kernel<<<dim3(64), blk, 0, stream>>>(x2, ln2w, ln2b, xlT);
  gemm_splitk<<<dim3(10,10,1), blk, 0, stream>>>(xlT, cwq, cwq, cwq, Pq, Pq, Pq, 1280, 128);
  epilogue_kernel<<<dim3(320), blk, 0, stream>>>(Pq, 10, 1280, cbq, nullptr, 0, qbuf, nullptr, nullptr);
  // SP=16, chunk=94 (16*94=1504 >= 1500)
  attn_fused<<<dim3(16,20,8), blk, 0, stream>>>(qbuf, ck, nullptr, cv, nullptr, nullptr, Pg, MLC, 1500, 1500, 94);
  attn_pv_combine<<<dim3(20,8), blk, 0, stream>>>(Pg, MLC, attT, 16);
  gemm_splitk<<<dim3(10,10,1), blk, 0, stream>>>(attT, cwo, cwo, cwo, Pq, Pq, Pq, 1280, 128);
  epilogue_kernel<<<dim3(320), blk, 0, stream>>>(Pq, 10, 1280, cbo, x2, 0, x3, nullptr, nullptr);

  // --- MLP ---
  ln_kernel<<<dim3(64), blk, 0, stream>>>(x3, ln3w, ln3b, xlT);
  gemm_splitk<<<dim3(40,10,1), blk, 0, stream>>>(xlT, w1, w1, w1, Pg, Pg, Pg, 5120, 128);
  epilogue_kernel<<<dim3(1280), blk, 0, stream>>>(Pg, 10, 5120, b1, nullptr, 1, nullptr, hT, nullptr);
  gemm_splitk<<<dim3(10,40,1), blk, 0, stream>>>(hT, w2, w2, w2, Pg, Pg, Pg, 1280, 128);
  epilogue_kernel<<<dim3(320), blk, 0, stream>>>(Pg, 40, 1280, b2, x3, 0, nullptr, nullptr, out_x);
}